// Round 13
// baseline (194.063 us; speedup 1.0000x reference)
//
#include <hip/hip_runtime.h>
#include <hip/hip_bf16.h>

#define BN    4112            // sequence length
#define NKR   4160            // padded key rows: 4048 main + 48 zero-pad + 64 mem
#define BNP   4160            // V^T col stride (= NKR)
#define BB    2
#define HH    8
#define NIMG_ 4096
#define NMAIN 4048
#define MROWS 8224            // BB*BN
// (1/sqrt(32)) * log2(e): folded into Q so attention uses raw v_exp_f32 (2^x)
#define QSCALE 0.25505402f

typedef __attribute__((ext_vector_type(8))) short short8;   // 8 bf16 (4 VGPRs)
typedef __attribute__((ext_vector_type(4))) float f32x4;
typedef __attribute__((ext_vector_type(16))) float f32x16;

__device__ __forceinline__ unsigned short f2bs(float x) { return __bfloat16_as_ushort(__float2bfloat16(x)); }
__device__ __forceinline__ unsigned pkbf(float a, float b) {
    __hip_bfloat162 h = __float22bfloat162_rn(make_float2(a, b));   // v_cvt_pk_bf16_f32
    unsigned u; __builtin_memcpy(&u, &h, 4); return u;
}
__device__ __forceinline__ float fexp2(float x) {
#if __has_builtin(__builtin_amdgcn_exp2f)
    return __builtin_amdgcn_exp2f(x);
#else
    return exp2f(x);
#endif
}

// ---------------- one-shot W fp32->bf16 conversion ---------------- (unchanged)
__global__ __launch_bounds__(256)
void prep_w(const float* __restrict__ Wq, const float* __restrict__ Wk,
            const float* __restrict__ Wv, const float* __restrict__ Wo,
            short* __restrict__ Wb)
{
    const int i   = blockIdx.x * 256 + threadIdx.x;
    const int m   = i >> 13;                    // 8192 threads per 65536-elem matrix
    const int off = (i & 8191) * 8;
    const float* W = (m == 0) ? Wq : (m == 1) ? Wk : (m == 2) ? Wv : Wo;
    float4 a0 = *(const float4*)(W + off), a1 = *(const float4*)(W + off + 4);
    *(uint4*)(Wb + (size_t)m * 65536 + off) =
        uint4{pkbf(a0.x, a0.y), pkbf(a0.z, a0.w), pkbf(a1.x, a1.y), pkbf(a1.z, a1.w)};
}

// ---------------- fused QKV projection: bf16 W + XCD-contiguous work decode ---------- (unchanged)
__global__ __launch_bounds__(256)
void qkv_mfma(const float* __restrict__ Aq, const float* __restrict__ Ak, const float* __restrict__ Av,
              const short* __restrict__ Wb,
              const float* __restrict__ bq, const float* __restrict__ bk, const float* __restrict__ bv,
              short* __restrict__ Qr, short* __restrict__ Kr, short* __restrict__ Vt,
              const float* __restrict__ fimg, const float* __restrict__ ftxt)
{
    __shared__ __align__(16) short Ws[2][64][72];
    __shared__ __align__(16) short Ds[2][64][72];

    // XCD-contiguous decode
    const int r_  = blockIdx.x & 7;
    const int j_  = blockIdx.x >> 3;          // 0..193
    const int W_  = r_ * 194 + j_;
    if (W_ >= 1548) return;                   // uniform early-out, before any barrier
    const int mode = W_ / 516;
    const int rem  = W_ - mode * 516;
    const int m0i  = rem >> 2;
    const int f0i  = rem & 3;

    const float* A    = (mode == 0) ? Aq : (mode == 1) ? Ak : Av;
    const float* bias = (mode == 0) ? bq : (mode == 1) ? bk : bv;

    const int t    = threadIdx.x;
    const int wave = t >> 6, lane = t & 63, q16 = lane & 15, quad = lane >> 4;
    const int f0 = f0i * 64;
    const int m0 = m0i * 64;
    const int sr = t >> 2, sc = (t & 3) * 16;
    const int arow = m0 + sr;
    const bool aval = arow < MROWS;
    const short* wp = Wb + (size_t)mode * 65536 + (size_t)(f0 + sr) * 256 + sc;
    const float* ap = A + (size_t)(aval ? arow : 0) * 256 + sc;

    f32x4 acc[4] = {{0,0,0,0},{0,0,0,0},{0,0,0,0},{0,0,0,0}};

    uint4 wr0, wr1, dr0, dr1;
    {
        wr0 = *(const uint4*)(wp); wr1 = *(const uint4*)(wp + 8);
        float4 a0 = *(const float4*)(ap);     float4 a1 = *(const float4*)(ap + 4);
        float4 a2 = *(const float4*)(ap + 8); float4 a3 = *(const float4*)(ap + 12);
        dr0 = uint4{pkbf(a0.x,a0.y), pkbf(a0.z,a0.w), pkbf(a1.x,a1.y), pkbf(a1.z,a1.w)};
        dr1 = uint4{pkbf(a2.x,a2.y), pkbf(a2.z,a2.w), pkbf(a3.x,a3.y), pkbf(a3.z,a3.w)};
    }
    *(uint4*)&Ws[0][sr][sc] = wr0; *(uint4*)&Ws[0][sr][sc + 8] = wr1;
    *(uint4*)&Ds[0][sr][sc] = dr0; *(uint4*)&Ds[0][sr][sc + 8] = dr1;
    __syncthreads();

    #pragma unroll
    for (int ki = 0; ki < 4; ++ki) {
        const int buf = ki & 1;
        if (ki < 3) {
            const int k1 = (ki + 1) * 64;
            wr0 = *(const uint4*)(wp + k1); wr1 = *(const uint4*)(wp + k1 + 8);
            float4 a0 = *(const float4*)(ap + k1);     float4 a1 = *(const float4*)(ap + k1 + 4);
            float4 a2 = *(const float4*)(ap + k1 + 8); float4 a3 = *(const float4*)(ap + k1 + 12);
            dr0 = uint4{pkbf(a0.x,a0.y), pkbf(a0.z,a0.w), pkbf(a1.x,a1.y), pkbf(a1.z,a1.w)};
            dr1 = uint4{pkbf(a2.x,a2.y), pkbf(a2.z,a2.w), pkbf(a3.x,a3.y), pkbf(a3.z,a3.w)};
        }
        #pragma unroll
        for (int ks = 0; ks < 2; ++ks) {
            const short8 af = *(const short8*)&Ws[buf][wave * 16 + q16][ks * 32 + quad * 8];
            #pragma unroll
            for (int ct = 0; ct < 4; ++ct) {
                const short8 bf = *(const short8*)&Ds[buf][ct * 16 + q16][ks * 32 + quad * 8];
                acc[ct] = __builtin_amdgcn_mfma_f32_16x16x32_bf16(af, bf, acc[ct], 0, 0, 0);
            }
        }
        if (ki < 3) {
            *(uint4*)&Ws[buf ^ 1][sr][sc] = wr0; *(uint4*)&Ws[buf ^ 1][sr][sc + 8] = wr1;
            *(uint4*)&Ds[buf ^ 1][sr][sc] = dr0; *(uint4*)&Ds[buf ^ 1][sr][sc + 8] = dr1;
            __syncthreads();
        }
    }

    const int fbase = f0 + wave * 16 + quad * 4;
    const float4 bb = *(const float4*)(bias + fbase);
    float vs[4][4];
    #pragma unroll
    for (int ct = 0; ct < 4; ++ct) {
        int n = m0 + ct * 16 + q16;
        float v0 = acc[ct][0] + bb.x, v1 = acc[ct][1] + bb.y;
        float v2 = acc[ct][2] + bb.z, v3 = acc[ct][3] + bb.w;
        int b  = (n >= BN) ? 1 : 0;
        int nb = n - b * BN;
        if (mode < 2) {
            int j0 = (fbase & 31) >> 1;
            const float* fr = (nb < NIMG_) ? (fimg + ((size_t)nb * 16 + j0) * 2)
                                           : (ftxt + ((size_t)(nb - NIMG_) * 16 + j0) * 2);
            float4 cs = *(const float4*)fr;
            float r0 = v0 * cs.x - v1 * cs.y, i0 = v0 * cs.y + v1 * cs.x;
            float r1 = v2 * cs.z - v3 * cs.w, i1 = v2 * cs.w + v3 * cs.z;
            v0 = r0; v1 = i0; v2 = r1; v3 = i1;
        }
        if (mode == 2) {
            vs[ct][0] = v0; vs[ct][1] = v1; vs[ct][2] = v2; vs[ct][3] = v3;
            continue;
        }
        if (n >= MROWS) continue;
        const int h = (fbase >> 5) & 7, hd = fbase & 31;
        if (mode == 0) {
            unsigned short* op = (unsigned short*)Qr + (((size_t)(b * HH + h) * BN + nb) * 32 + hd);
            *(uint2*)op = uint2{pkbf(v0 * QSCALE, v1 * QSCALE), pkbf(v2 * QSCALE, v3 * QSCALE)};
        } else {
            int nk = nb + ((nb >= NMAIN) ? 48 : 0);
            unsigned short* op = (unsigned short*)Kr + (((size_t)(b * HH + h) * NKR + nk) * 32 + hd);
            *(uint2*)op = uint2{pkbf(v0, v1), pkbf(v2, v3)};
        }
    }

    if (mode == 2) {
        short (*Tr)[72] = Ds[0];
        const int fl = wave * 16 + quad * 4;
        #pragma unroll
        for (int ct = 0; ct < 4; ++ct) {
            const int nl = ct * 16 + q16;
            Tr[fl + 0][nl] = (short)f2bs(vs[ct][0]);
            Tr[fl + 1][nl] = (short)f2bs(vs[ct][1]);
            Tr[fl + 2][nl] = (short)f2bs(vs[ct][2]);
            Tr[fl + 3][nl] = (short)f2bs(vs[ct][3]);
        }
        __syncthreads();
        const int h0 = (f0 >> 5) & 7;
        #pragma unroll
        for (int ii = 0; ii < 2; ++ii) {
            const int r  = ii * 32 + (t >> 3);
            const int c8 = (t & 7) * 8;
            const int ng = m0 + c8;
            if (ng < MROWS) {
                uint4 val = *(const uint4*)&Tr[r][c8];
                int b  = (ng >= BN) ? 1 : 0;
                int nb = ng - b * BN;
                int nk = nb + ((nb >= NMAIN) ? 48 : 0);
                int h  = h0 + (r >> 5), hd = r & 31;
                unsigned short* op = (unsigned short*)Vt + ((size_t)(b * HH + h) * 32 + hd) * BNP + nk;
                *(uint4*)op = val;
            }
        }
    }

    if (f0i == 0 && m0i < 16 && t < 192) {
        const int bh = m0i;
        if (mode == 1) {
            short* base = Kr + (size_t)bh * NKR * 32 + (size_t)NMAIN * 32;
            *(uint4*)(base + t * 8) = uint4{0u, 0u, 0u, 0u};
        } else if (mode == 2) {
            short* base = Vt + (size_t)bh * 32 * BNP + (size_t)(t / 6) * BNP + NMAIN + (t % 6) * 8;
            *(uint4*)base = uint4{0u, 0u, 0u, 0u};
        }
    }
}

// ---------------- MFMA flash attention: R9 structure + L-sum on the matrix pipe ------
// For the 32 main tiles, L is accumulated by an extra MFMA per P-fragment with A = ones
// (oL = mfma(ones8, pb, oL)) — every output reg equals the full k-sum (identical A rows;
// each MFMA sums k=0..15 across BOTH lane halves), so LA = oL[0] with NO shfl merge.
// Removes ~64 VALU adds/tile from the 50%-busy VALU pipe; adds 4 MFMA/tile to the
// 17%-busy matrix pipe. Mem tile (1 of 33) keeps the VALU path. bf16-consistent L (sums
// the same bf16 P used for O); pads contribute exactly 1.0 -> -48 correction unchanged.
__global__ __launch_bounds__(256, 4)
void attn_mfma(const short* __restrict__ Qr, const short* __restrict__ Kr,
               const short* __restrict__ Vt, unsigned short* __restrict__ AO)
{
    __shared__ __align__(16) short Ks[2][2][64][40];   // [group][buf] 20480 B
    __shared__ __align__(16) short Vs[2][2][32][72];   // [group][buf] 18432 B (cols 0..63 used)

    const int t    = threadIdx.x;
    const int wave = t >> 6, lane = t & 63, q32 = lane & 31, hi = lane >> 5;
    const int grp  = wave >> 1, w2 = wave & 1;

    // XCD-aware decode: blocks with the same bh land on one XCD (b%8 round-robin)
    const int b_   = blockIdx.x;
    const int idx  = b_ >> 3;
    const int bh   = ((b_ & 7) << 1) + (idx >= 65 ? 1 : 0);
    const int bx   = idx - (idx >= 65 ? 65 : 0);

    const int q  = bx * 64 + w2 * 32 + q32;
    const int qc = (q < BN) ? q : (BN - 1);
    const short* qp = Qr + ((size_t)bh * BN + qc) * 32 + hi * 8;
    const short8 qf0 = *(const short8*)(qp);
    const short8 qf1 = *(const short8*)(qp + 16);

    // A-operand of all-ones (bf16 1.0 = 0x3F80) for the L-sum MFMA
    short8 ones8;
    {
        uint4 ou = uint4{0x3F803F80u, 0x3F803F80u, 0x3F803F80u, 0x3F803F80u};
        __builtin_memcpy(&ones8, &ou, 16);
    }

    f32x16 oAx = {0,0,0,0,0,0,0,0,0,0,0,0,0,0,0,0};
    f32x16 oAy = {0,0,0,0,0,0,0,0,0,0,0,0,0,0,0,0};
    f32x16 oBx = {0,0,0,0,0,0,0,0,0,0,0,0,0,0,0,0};
    f32x16 oL  = {0,0,0,0,0,0,0,0,0,0,0,0,0,0,0,0};
    const f32x16 z16 = {0,0,0,0,0,0,0,0,0,0,0,0,0,0,0,0};
    float LB = 0.f;

    const int tg = t & 127;                 // group-local thread id (128 per group)
    const int kr = tg >> 2, kc = tg & 3;    // K: rows kr, kr+32
    const int vr = tg >> 3, vc = tg & 7;    // V: rows vr, vr+16
    const short* kg = Kr + (size_t)bh * NKR * 32 + (size_t)grp * 65536 + (size_t)kr * 32 + kc * 8;
    const short* vg = Vt + (size_t)bh * 32 * BNP + (size_t)vr * BNP + grp * 2048
                         + (vc >> 1) * 16 + (vc & 1) * 4;
    const int ntiles = 32 + grp;            // group 0: 32 tiles, group 1: 33 (incl. mem)

    // main-tile path: L via ones-MFMA (no VALU adds)
    auto tileA = [&](int buf) {
        const short8 kf00 = *(const short8*)&Ks[grp][buf][q32][hi * 8];
        const short8 kf01 = *(const short8*)&Ks[grp][buf][q32][16 + hi * 8];
        const short8 kf10 = *(const short8*)&Ks[grp][buf][32 + q32][hi * 8];
        const short8 kf11 = *(const short8*)&Ks[grp][buf][32 + q32][16 + hi * 8];
        f32x16 s0 = __builtin_amdgcn_mfma_f32_32x32x16_bf16(kf00, qf0, z16, 0, 0, 0);
        f32x16 s1 = __builtin_amdgcn_mfma_f32_32x32x16_bf16(kf10, qf0, z16, 0, 0, 0);
        s0 = __builtin_amdgcn_mfma_f32_32x32x16_bf16(kf01, qf1, s0, 0, 0, 0);
        s1 = __builtin_amdgcn_mfma_f32_32x32x16_bf16(kf11, qf1, s1, 0, 0, 0);
        float p0[16], p1[16];
        #pragma unroll
        for (int r = 0; r < 16; ++r) p0[r] = fexp2(s0[r]);
        #pragma unroll
        for (int r = 0; r < 16; ++r) p1[r] = fexp2(s1[r]);
        #pragma unroll
        for (int m = 0; m < 2; ++m) {
            uint4 pbu = uint4{pkbf(p0[8*m+0], p0[8*m+1]), pkbf(p0[8*m+2], p0[8*m+3]),
                              pkbf(p0[8*m+4], p0[8*m+5]), pkbf(p0[8*m+6], p0[8*m+7])};
            short8 pb; __builtin_memcpy(&pb, &pbu, 16);
            const short8 vf = *(const short8*)&Vs[grp][buf][q32][m * 16 + hi * 8];
            oAx = __builtin_amdgcn_mfma_f32_32x32x16_bf16(vf, pb, oAx, 0, 0, 0);
            oL  = __builtin_amdgcn_mfma_f32_32x32x16_bf16(ones8, pb, oL, 0, 0, 0);
        }
        #pragma unroll
        for (int m = 0; m < 2; ++m) {
            uint4 pbu = uint4{pkbf(p1[8*m+0], p1[8*m+1]), pkbf(p1[8*m+2], p1[8*m+3]),
                              pkbf(p1[8*m+4], p1[8*m+5]), pkbf(p1[8*m+6], p1[8*m+7])};
            short8 pb; __builtin_memcpy(&pb, &pbu, 16);
            const short8 vf = *(const short8*)&Vs[grp][buf][q32][32 + m * 16 + hi * 8];
            oAy = __builtin_amdgcn_mfma_f32_32x32x16_bf16(vf, pb, oAy, 0, 0, 0);
            oL  = __builtin_amdgcn_mfma_f32_32x32x16_bf16(ones8, pb, oL, 0, 0, 0);
        }
    };

    // mem-tile path (1 of 33): original VALU L-sum into LB
    auto tileB = [&](int buf) {
        const short8 kf00 = *(const short8*)&Ks[grp][buf][q32][hi * 8];
        const short8 kf01 = *(const short8*)&Ks[grp][buf][q32][16 + hi * 8];
        const short8 kf10 = *(const short8*)&Ks[grp][buf][32 + q32][hi * 8];
        const short8 kf11 = *(const short8*)&Ks[grp][buf][32 + q32][16 + hi * 8];
        f32x16 s0 = __builtin_amdgcn_mfma_f32_32x32x16_bf16(kf00, qf0, z16, 0, 0, 0);
        f32x16 s1 = __builtin_amdgcn_mfma_f32_32x32x16_bf16(kf10, qf0, z16, 0, 0, 0);
        s0 = __builtin_amdgcn_mfma_f32_32x32x16_bf16(kf01, qf1, s0, 0, 0, 0);
        s1 = __builtin_amdgcn_mfma_f32_32x32x16_bf16(kf11, qf1, s1, 0, 0, 0);
        float p0[16], p1[16];
        #pragma unroll
        for (int r = 0; r < 16; ++r) p0[r] = fexp2(s0[r]);
        #pragma unroll
        for (int r = 0; r < 16; ++r) p1[r] = fexp2(s1[r]);
        float l0 = (((p0[0]+p0[1])+(p0[2]+p0[3])) + ((p0[4]+p0[5])+(p0[6]+p0[7])))
                 + (((p0[8]+p0[9])+(p0[10]+p0[11])) + ((p0[12]+p0[13])+(p0[14]+p0[15])));
        float l1 = (((p1[0]+p1[1])+(p1[2]+p1[3])) + ((p1[4]+p1[5])+(p1[6]+p1[7])))
                 + (((p1[8]+p1[9])+(p1[10]+p1[11])) + ((p1[12]+p1[13])+(p1[14]+p1[15])));
        #pragma unroll
        for (int m = 0; m < 2; ++m) {
            uint4 pbu = uint4{pkbf(p0[8*m+0], p0[8*m+1]), pkbf(p0[8*m+2], p0[8*m+3]),
                              pkbf(p0[8*m+4], p0[8*m+5]), pkbf(p0[8*m+6], p0[8*m+7])};
            short8 pb; __builtin_memcpy(&pb, &pbu, 16);
            const short8 vf = *(const short8*)&Vs[grp][buf][q32][m * 16 + hi * 8];
            oBx = __builtin_amdgcn_mfma_f32_32x32x16_bf16(vf, pb, oBx, 0, 0, 0);
        }
        #pragma unroll
        for (int m = 0; m < 2; ++m) {
            uint4 pbu = uint4{pkbf(p1[8*m+0], p1[8*m+1]), pkbf(p1[8*m+2], p1[8*m+3]),
                              pkbf(p1[8*m+4], p1[8*m+5]), pkbf(p1[8*m+6], p1[8*m+7])};
            short8 pb; __builtin_memcpy(&pb, &pbu, 16);
            const short8 vf = *(const short8*)&Vs[grp][buf][q32][32 + m * 16 + hi * 8];
            oBx = __builtin_amdgcn_mfma_f32_32x32x16_bf16(vf, pb, oBx, 0, 0, 0);
        }
        LB += l0 + l1;
    };

    // stage each group's tile 0 (2 uint4 K + 2 permuted V rows per thread)
    *(uint4*)&Ks[grp][0][kr][kc * 8]      = *(const uint4*)(kg);
    *(uint4*)&Ks[grp][0][kr + 32][kc * 8] = *(const uint4*)(kg + 1024);
    {
        uint2 a0 = *(const uint2*)(vg),              b0 = *(const uint2*)(vg + 8);
        uint2 a1 = *(const uint2*)(vg + 16 * BNP),   b1 = *(const uint2*)(vg + 16 * BNP + 8);
        *(uint4*)&Vs[grp][0][vr][vc * 8]      = uint4{a0.x, a0.y, b0.x, b0.y};
        *(uint4*)&Vs[grp][0][vr + 16][vc * 8] = uint4{a1.x, a1.y, b1.x, b1.y};
    }
    __syncthreads();

    for (int it = 0; it < 33; ++it) {       // 33 uniform barriers; group 0 idles at it=32
        const int buf = it & 1;
        uint4 kreg0, kreg1; uint2 va0, vb0, va1, vb1;
        const bool pre = (it + 1) < ntiles;
        if (pre) {
            const short* kp = kg + (size_t)(it + 1) * 2048;
            kreg0 = *(const uint4*)(kp);
            kreg1 = *(const uint4*)(kp + 1024);
            const short* vp = vg + (it + 1) * 64;
            va0 = *(const uint2*)(vp);            vb0 = *(const uint2*)(vp + 8);
            va1 = *(const uint2*)(vp + 16 * BNP); vb1 = *(const uint2*)(vp + 16 * BNP + 8);
        }
        if (it < ntiles) {
            __builtin_amdgcn_s_setprio(1);
            if (grp == 0 || it < 32) tileA(buf);
            else                     tileB(buf);   // tile 64 = mem segment
            __builtin_amdgcn_s_setprio(0);
        }
        if (pre) {
            *(uint4*)&Ks[grp][buf ^ 1][kr][kc * 8]      = kreg0;
            *(uint4*)&Ks[grp][buf ^ 1][kr + 32][kc * 8] = kreg1;
            *(uint4*)&Vs[grp][buf ^ 1][vr][vc * 8]      = uint4{va0.x, va0.y, vb0.x, vb0.y};
            *(uint4*)&Vs[grp][buf ^ 1][vr + 16][vc * 8] = uint4{va1.x, va1.y, vb1.x, vb1.y};
        }
        __syncthreads();
    }

    // combine the two per-half accumulators
    f32x16 oA = oAx + oAy;
    f32x16 oB = oBx;
    float LA = oL[0];                       // every reg of oL holds the full k-sum
    LB += __shfl_xor(LB, 32);

    // exchange group-0 partials through LDS (reuse Ks; all tile reads are done)
    float* ex = (float*)&Ks[0][0][0][0];    // [w2*64+lane]*20 : oA[16], LA  (10240 B used)
    const int slot = (w2 * 64 + lane) * 20;
    if (grp == 0) {
        #pragma unroll
        for (int i = 0; i < 4; ++i)
            *(f32x4*)(ex + slot + 4 * i) = f32x4{oA[4*i], oA[4*i+1], oA[4*i+2], oA[4*i+3]};
        ex[slot + 16] = LA;
    }
    __syncthreads();

    if (grp == 1 && q < BN) {
        float LT = LA + ex[slot + 16] - 48.f;     // 48 zero-pad keys contributed p=1 each
        const float iA = 1.f / LT, iB = 1.f / LB;
        const int b = bh >> 3, h = bh & 7;
        unsigned short* ap = AO + ((size_t)b * BN + q) * 256 + h * 32;
        #pragma unroll
        for (int k = 0; k < 4; ++k) {
            f32x4 a = *(const f32x4*)(ex + slot + 4 * k);
            float w0 = (oA[4*k+0] + a[0]) * iA + oB[4*k+0] * iB;
            float w1 = (oA[4*k+1] + a[1]) * iA + oB[4*k+1] * iB;
            float w2 = (oA[4*k+2] + a[2]) * iA + oB[4*k+2] * iB;
            float w3 = (oA[4*k+3] + a[3]) * iA + oB[4*k+3] * iB;
            // regs 4k..4k+3 -> hd = 8k + 4*hi + {0..3}
            *(uint2*)(ap + 8 * k + 4 * hi) = uint2{pkbf(w0, w1), pkbf(w2, w3)};
        }
    }
}

// ---------------- output GEMM: bf16 W + XCD-contiguous work decode ---------------- (unchanged)
__global__ __launch_bounds__(256)
void gemm_out(const unsigned short* __restrict__ A, const short* __restrict__ Wb,
              const float* __restrict__ bias, float* __restrict__ out)
{
    __shared__ __align__(16) short Ws[2][64][72];
    __shared__ __align__(16) short Ds[2][64][72];

    const int r_ = blockIdx.x & 7;
    const int j_ = blockIdx.x >> 3;           // 0..64
    const int W_ = r_ * 65 + j_;
    if (W_ >= 516) return;                    // uniform early-out, before any barrier
    const int m0i = W_ >> 2, f0i = W_ & 3;

    const int t    = threadIdx.x;
    const int wave = t >> 6, lane = t & 63, q16 = lane & 15, quad = lane >> 4;
    const int f0 = f0i * 64, m0 = m0i * 64;
    const int sr = t >> 2, sc = (t & 3) * 16;
    const int arow = m0 + sr;
    const bool aval = arow < MROWS;
    const short* wp = Wb + (size_t)3 * 65536 + (size_t)(f0 + sr) * 256 + sc;
    const unsigned short* ap = A + (size_t)(aval ? arow : 0) * 256 + sc;

    f32x4 acc[4] = {{0,0,0,0},{0,0,0,0},{0,0,0,0},{0,0,0,0}};

    uint4 wr0, wr1, dr0, dr1;
    {
        wr0 = *(const uint4*)(wp); wr1 = *(const uint4*)(wp + 8);
        dr0 = *(const uint4*)(ap); dr1 = *(const uint4*)(ap + 8);
    }
    *(uint4*)&Ws[0][sr][sc] = wr0; *(uint4*)&Ws[0][sr][sc + 8] = wr1;
    *(uint4*)&Ds[0][sr][sc] = dr0; *(uint4*)&Ds[0][sr][sc + 8] = dr1;
    __syncthreads();

    #pragma unroll
    for (int ki = 0; ki < 4; ++ki) {
        const int buf = ki & 1;
        if (ki < 3) {
            const int k1 = (ki + 1) * 64;
            wr0 = *(const uint4*)(wp + k1); wr1 = *(const uint4*)(wp + k1 + 8);
            dr0 = *(const uint4*)(ap + k1); dr1 = *(const uint4*)(ap + k1 + 8);
        }
        #pragma unroll
        for (int ks = 0; ks < 2; ++ks) {
            const short8 af = *(const short8*)&Ws[buf][wave * 16 + q16][ks * 32 + quad * 8];
            #pragma unroll
            for (int ct = 0; ct < 4; ++ct) {
                const short8 bf = *(const short8*)&Ds[buf][ct * 16 + q16][ks * 32 + quad * 8];
                acc[ct] = __builtin_amdgcn_mfma_f32_16x16x32_bf16(af, bf, acc[ct], 0, 0, 0);
            }
        }
        if (ki < 3) {
            *(uint4*)&Ws[buf ^ 1][sr][sc] = wr0; *(uint4*)&Ws[buf ^ 1][sr][sc + 8] = wr1;
            *(uint4*)&Ds[buf ^ 1][sr][sc] = dr0; *(uint4*)&Ds[buf ^ 1][sr][sc + 8] = dr1;
            __syncthreads();
        }
    }

    const int fbase = f0 + wave * 16 + quad * 4;
    const float4 bb = *(const float4*)(bias + fbase);
    #pragma unroll
    for (int ct = 0; ct < 4; ++ct) {
        int n = m0 + ct * 16 + q16;
        if (n >= MROWS) continue;
        float* op = out + (size_t)n * 256 + fbase;
        *(float4*)op = float4{acc[ct][0] + bb.x, acc[ct][1] + bb.y,
                              acc[ct][2] + bb.z, acc[ct][3] + bb.w};
    }
}

extern "C" void kernel_launch(void* const* d_in, const int* in_sizes, int n_in,
                              void* d_out, int out_size, void* d_ws, size_t ws_size,
                              hipStream_t stream)
{
    (void)in_sizes; (void)n_in; (void)out_size; (void)ws_size;
    const float* q    = (const float*)d_in[0];
    const float* k    = (const float*)d_in[1];
    const float* v    = (const float*)d_in[2];
    const float* fimg = (const float*)d_in[3];
    const float* ftxt = (const float*)d_in[4];
    const float* Wq   = (const float*)d_in[5];
    const float* bq   = (const float*)d_in[6];
    const float* Wk   = (const float*)d_in[7];
    const float* bk   = (const float*)d_in[8];
    const float* Wv   = (const float*)d_in[9];
    const float* bv   = (const float*)d_in[10];
    const float* Wo   = (const float*)d_in[11];
    const float* bo   = (const float*)d_in[12];
    // d_in[13] = num_k_exclude_rope = 64 (compiled in)

    // workspace: Qr bf16 [16][BN][32]; Kr bf16 [16][NKR][32]; Vt bf16 [16][32][BNP];
    // AO bf16 [BB][BN][256]; Wb bf16 [4][256][256]. Total 17,465,344 B (~16.7 MB)
    char* w = (char*)d_ws;
    short*          Qr = (short*)(w);                    //  4,210,688
    short*          Kr = (short*)(w + 4210688);          //  4,259,840
    short*          Vt = (short*)(w + 8470528);          //  4,259,840
    unsigned short* AO = (unsigned short*)(w + 12730368);//  4,210,688
    short*          Wb = (short*)(w + 16941056);         //    524,288

    prep_w<<<dim3(128), 256, 0, stream>>>(Wq, Wk, Wv, Wo, Wb);
    qkv_mfma<<<dim3(1552), 256, 0, stream>>>(q, k, v, Wb, bq, bk, bv,
                                             Qr, Kr, Vt, fimg, ftxt);
    attn_mfma<<<dim3(1040), 256, 0, stream>>>(Qr, Kr, Vt, AO);
    gemm_out<<<dim3(520), 256, 0, stream>>>(AO, Wb, bo, (float*)d_out);
}

// Round 14
// 187.562 us; speedup vs baseline: 1.0347x; 1.0347x over previous
//
#include <hip/hip_runtime.h>
#include <hip/hip_bf16.h>

#define BN    4112            // sequence length
#define NKR   4160            // padded key rows: 4048 main + 48 zero-pad + 64 mem
#define BNP   4160            // V^T col stride (= NKR)
#define BB    2
#define HH    8
#define NIMG_ 4096
#define NMAIN 4048
#define MROWS 8224            // BB*BN
// (1/sqrt(32)) * log2(e): folded into Q so attention uses raw v_exp_f32 (2^x)
#define QSCALE 0.25505402f

typedef __attribute__((ext_vector_type(8))) short short8;   // 8 bf16 (4 VGPRs)
typedef __attribute__((ext_vector_type(4))) float f32x4;
typedef __attribute__((ext_vector_type(16))) float f32x16;

__device__ __forceinline__ unsigned short f2bs(float x) { return __bfloat16_as_ushort(__float2bfloat16(x)); }
__device__ __forceinline__ unsigned pkbf(float a, float b) {
    __hip_bfloat162 h = __float22bfloat162_rn(make_float2(a, b));   // v_cvt_pk_bf16_f32
    unsigned u; __builtin_memcpy(&u, &h, 4); return u;
}
__device__ __forceinline__ float fexp2(float x) {
#if __has_builtin(__builtin_amdgcn_exp2f)
    return __builtin_amdgcn_exp2f(x);
#else
    return exp2f(x);
#endif
}

// ---------------- one-shot W fp32->bf16 conversion ----------------
__global__ __launch_bounds__(256)
void prep_w(const float* __restrict__ Wq, const float* __restrict__ Wk,
            const float* __restrict__ Wv, const float* __restrict__ Wo,
            short* __restrict__ Wb)
{
    const int i   = blockIdx.x * 256 + threadIdx.x;
    const int m   = i >> 13;                    // 8192 threads per 65536-elem matrix
    const int off = (i & 8191) * 8;
    const float* W = (m == 0) ? Wq : (m == 1) ? Wk : (m == 2) ? Wv : Wo;
    float4 a0 = *(const float4*)(W + off), a1 = *(const float4*)(W + off + 4);
    *(uint4*)(Wb + (size_t)m * 65536 + off) =
        uint4{pkbf(a0.x, a0.y), pkbf(a0.z, a0.w), pkbf(a1.x, a1.y), pkbf(a1.z, a1.w)};
}

// ---------------- fused QKV projection: bf16 W + XCD-contiguous work decode ----------
__global__ __launch_bounds__(256)
void qkv_mfma(const float* __restrict__ Aq, const float* __restrict__ Ak, const float* __restrict__ Av,
              const short* __restrict__ Wb,
              const float* __restrict__ bq, const float* __restrict__ bk, const float* __restrict__ bv,
              short* __restrict__ Qr, short* __restrict__ Kr, short* __restrict__ Vt,
              const float* __restrict__ fimg, const float* __restrict__ ftxt)
{
    __shared__ __align__(16) short Ws[2][64][72];
    __shared__ __align__(16) short Ds[2][64][72];

    // XCD-contiguous decode
    const int r_  = blockIdx.x & 7;
    const int j_  = blockIdx.x >> 3;          // 0..193
    const int W_  = r_ * 194 + j_;
    if (W_ >= 1548) return;                   // uniform early-out, before any barrier
    const int mode = W_ / 516;
    const int rem  = W_ - mode * 516;
    const int m0i  = rem >> 2;
    const int f0i  = rem & 3;

    const float* A    = (mode == 0) ? Aq : (mode == 1) ? Ak : Av;
    const float* bias = (mode == 0) ? bq : (mode == 1) ? bk : bv;

    const int t    = threadIdx.x;
    const int wave = t >> 6, lane = t & 63, q16 = lane & 15, quad = lane >> 4;
    const int f0 = f0i * 64;
    const int m0 = m0i * 64;
    const int sr = t >> 2, sc = (t & 3) * 16;
    const int arow = m0 + sr;
    const bool aval = arow < MROWS;
    const short* wp = Wb + (size_t)mode * 65536 + (size_t)(f0 + sr) * 256 + sc;
    const float* ap = A + (size_t)(aval ? arow : 0) * 256 + sc;

    f32x4 acc[4] = {{0,0,0,0},{0,0,0,0},{0,0,0,0},{0,0,0,0}};

    uint4 wr0, wr1, dr0, dr1;
    {
        wr0 = *(const uint4*)(wp); wr1 = *(const uint4*)(wp + 8);
        float4 a0 = *(const float4*)(ap);     float4 a1 = *(const float4*)(ap + 4);
        float4 a2 = *(const float4*)(ap + 8); float4 a3 = *(const float4*)(ap + 12);
        dr0 = uint4{pkbf(a0.x,a0.y), pkbf(a0.z,a0.w), pkbf(a1.x,a1.y), pkbf(a1.z,a1.w)};
        dr1 = uint4{pkbf(a2.x,a2.y), pkbf(a2.z,a2.w), pkbf(a3.x,a3.y), pkbf(a3.z,a3.w)};
    }
    *(uint4*)&Ws[0][sr][sc] = wr0; *(uint4*)&Ws[0][sr][sc + 8] = wr1;
    *(uint4*)&Ds[0][sr][sc] = dr0; *(uint4*)&Ds[0][sr][sc + 8] = dr1;
    __syncthreads();

    #pragma unroll
    for (int ki = 0; ki < 4; ++ki) {
        const int buf = ki & 1;
        if (ki < 3) {
            const int k1 = (ki + 1) * 64;
            wr0 = *(const uint4*)(wp + k1); wr1 = *(const uint4*)(wp + k1 + 8);
            float4 a0 = *(const float4*)(ap + k1);     float4 a1 = *(const float4*)(ap + k1 + 4);
            float4 a2 = *(const float4*)(ap + k1 + 8); float4 a3 = *(const float4*)(ap + k1 + 12);
            dr0 = uint4{pkbf(a0.x,a0.y), pkbf(a0.z,a0.w), pkbf(a1.x,a1.y), pkbf(a1.z,a1.w)};
            dr1 = uint4{pkbf(a2.x,a2.y), pkbf(a2.z,a2.w), pkbf(a3.x,a3.y), pkbf(a3.z,a3.w)};
        }
        #pragma unroll
        for (int ks = 0; ks < 2; ++ks) {
            const short8 af = *(const short8*)&Ws[buf][wave * 16 + q16][ks * 32 + quad * 8];
            #pragma unroll
            for (int ct = 0; ct < 4; ++ct) {
                const short8 bf = *(const short8*)&Ds[buf][ct * 16 + q16][ks * 32 + quad * 8];
                acc[ct] = __builtin_amdgcn_mfma_f32_16x16x32_bf16(af, bf, acc[ct], 0, 0, 0);
            }
        }
        if (ki < 3) {
            *(uint4*)&Ws[buf ^ 1][sr][sc] = wr0; *(uint4*)&Ws[buf ^ 1][sr][sc + 8] = wr1;
            *(uint4*)&Ds[buf ^ 1][sr][sc] = dr0; *(uint4*)&Ds[buf ^ 1][sr][sc + 8] = dr1;
            __syncthreads();
        }
    }

    const int fbase = f0 + wave * 16 + quad * 4;
    const float4 bb = *(const float4*)(bias + fbase);
    float vs[4][4];
    #pragma unroll
    for (int ct = 0; ct < 4; ++ct) {
        int n = m0 + ct * 16 + q16;
        float v0 = acc[ct][0] + bb.x, v1 = acc[ct][1] + bb.y;
        float v2 = acc[ct][2] + bb.z, v3 = acc[ct][3] + bb.w;
        int b  = (n >= BN) ? 1 : 0;
        int nb = n - b * BN;
        if (mode < 2) {
            int j0 = (fbase & 31) >> 1;
            const float* fr = (nb < NIMG_) ? (fimg + ((size_t)nb * 16 + j0) * 2)
                                           : (ftxt + ((size_t)(nb - NIMG_) * 16 + j0) * 2);
            float4 cs = *(const float4*)fr;
            float r0 = v0 * cs.x - v1 * cs.y, i0 = v0 * cs.y + v1 * cs.x;
            float r1 = v2 * cs.z - v3 * cs.w, i1 = v2 * cs.w + v3 * cs.z;
            v0 = r0; v1 = i0; v2 = r1; v3 = i1;
        }
        if (mode == 2) {
            vs[ct][0] = v0; vs[ct][1] = v1; vs[ct][2] = v2; vs[ct][3] = v3;
            continue;
        }
        if (n >= MROWS) continue;
        const int h = (fbase >> 5) & 7, hd = fbase & 31;
        if (mode == 0) {
            unsigned short* op = (unsigned short*)Qr + (((size_t)(b * HH + h) * BN + nb) * 32 + hd);
            *(uint2*)op = uint2{pkbf(v0 * QSCALE, v1 * QSCALE), pkbf(v2 * QSCALE, v3 * QSCALE)};
        } else {
            int nk = nb + ((nb >= NMAIN) ? 48 : 0);
            unsigned short* op = (unsigned short*)Kr + (((size_t)(b * HH + h) * NKR + nk) * 32 + hd);
            *(uint2*)op = uint2{pkbf(v0, v1), pkbf(v2, v3)};
        }
    }

    if (mode == 2) {
        short (*Tr)[72] = Ds[0];
        const int fl = wave * 16 + quad * 4;
        #pragma unroll
        for (int ct = 0; ct < 4; ++ct) {
            const int nl = ct * 16 + q16;
            Tr[fl + 0][nl] = (short)f2bs(vs[ct][0]);
            Tr[fl + 1][nl] = (short)f2bs(vs[ct][1]);
            Tr[fl + 2][nl] = (short)f2bs(vs[ct][2]);
            Tr[fl + 3][nl] = (short)f2bs(vs[ct][3]);
        }
        __syncthreads();
        const int h0 = (f0 >> 5) & 7;
        #pragma unroll
        for (int ii = 0; ii < 2; ++ii) {
            const int r  = ii * 32 + (t >> 3);
            const int c8 = (t & 7) * 8;
            const int ng = m0 + c8;
            if (ng < MROWS) {
                uint4 val = *(const uint4*)&Tr[r][c8];
                int b  = (ng >= BN) ? 1 : 0;
                int nb = ng - b * BN;
                int nk = nb + ((nb >= NMAIN) ? 48 : 0);
                int h  = h0 + (r >> 5), hd = r & 31;
                unsigned short* op = (unsigned short*)Vt + ((size_t)(b * HH + h) * 32 + hd) * BNP + nk;
                *(uint4*)op = val;
            }
        }
    }

    if (f0i == 0 && m0i < 16 && t < 192) {
        const int bh = m0i;
        if (mode == 1) {
            short* base = Kr + (size_t)bh * NKR * 32 + (size_t)NMAIN * 32;
            *(uint4*)(base + t * 8) = uint4{0u, 0u, 0u, 0u};
        } else if (mode == 2) {
            short* base = Vt + (size_t)bh * 32 * BNP + (size_t)(t / 6) * BNP + NMAIN + (t % 6) * 8;
            *(uint4*)base = uint4{0u, 0u, 0u, 0u};
        }
    }
}

// ---------------- MFMA flash attention: EXACT R9/R11 structure (best: 85.8-86.0 us) ---
__global__ __launch_bounds__(256, 4)
void attn_mfma(const short* __restrict__ Qr, const short* __restrict__ Kr,
               const short* __restrict__ Vt, unsigned short* __restrict__ AO)
{
    __shared__ __align__(16) short Ks[2][2][64][40];   // [group][buf] 20480 B
    __shared__ __align__(16) short Vs[2][2][32][72];   // [group][buf] 18432 B (cols 0..63 used)

    const int t    = threadIdx.x;
    const int wave = t >> 6, lane = t & 63, q32 = lane & 31, hi = lane >> 5;
    const int grp  = wave >> 1, w2 = wave & 1;

    // XCD-aware decode: blocks with the same bh land on one XCD (b%8 round-robin)
    const int b_   = blockIdx.x;
    const int idx  = b_ >> 3;
    const int bh   = ((b_ & 7) << 1) + (idx >= 65 ? 1 : 0);
    const int bx   = idx - (idx >= 65 ? 65 : 0);

    const int q  = bx * 64 + w2 * 32 + q32;
    const int qc = (q < BN) ? q : (BN - 1);
    const short* qp = Qr + ((size_t)bh * BN + qc) * 32 + hi * 8;
    const short8 qf0 = *(const short8*)(qp);
    const short8 qf1 = *(const short8*)(qp + 16);

    f32x16 oAx = {0,0,0,0,0,0,0,0,0,0,0,0,0,0,0,0};
    f32x16 oAy = {0,0,0,0,0,0,0,0,0,0,0,0,0,0,0,0};
    f32x16 oBx = {0,0,0,0,0,0,0,0,0,0,0,0,0,0,0,0};
    const f32x16 z16 = {0,0,0,0,0,0,0,0,0,0,0,0,0,0,0,0};
    float LA = 0.f, LB = 0.f;

    const int tg = t & 127;                 // group-local thread id (128 per group)
    const int kr = tg >> 2, kc = tg & 3;    // K: rows kr, kr+32
    const int vr = tg >> 3, vc = tg & 7;    // V: rows vr, vr+16
    const short* kg = Kr + (size_t)bh * NKR * 32 + (size_t)grp * 65536 + (size_t)kr * 32 + kc * 8;
    const short* vg = Vt + (size_t)bh * 32 * BNP + (size_t)vr * BNP + grp * 2048
                         + (vc >> 1) * 16 + (vc & 1) * 4;
    const int ntiles = 32 + grp;            // group 0: 32 tiles, group 1: 33 (incl. mem)

    // two independent chains (keys 0..31 -> ox, keys 32..63 -> oy) for ILP
    auto tile = [&](int buf, f32x16& ox, f32x16& oy, float& L) {
        const short8 kf00 = *(const short8*)&Ks[grp][buf][q32][hi * 8];
        const short8 kf01 = *(const short8*)&Ks[grp][buf][q32][16 + hi * 8];
        const short8 kf10 = *(const short8*)&Ks[grp][buf][32 + q32][hi * 8];
        const short8 kf11 = *(const short8*)&Ks[grp][buf][32 + q32][16 + hi * 8];
        f32x16 s0 = __builtin_amdgcn_mfma_f32_32x32x16_bf16(kf00, qf0, z16, 0, 0, 0);
        f32x16 s1 = __builtin_amdgcn_mfma_f32_32x32x16_bf16(kf10, qf0, z16, 0, 0, 0);
        s0 = __builtin_amdgcn_mfma_f32_32x32x16_bf16(kf01, qf1, s0, 0, 0, 0);
        s1 = __builtin_amdgcn_mfma_f32_32x32x16_bf16(kf11, qf1, s1, 0, 0, 0);
        float p0[16], p1[16];
        #pragma unroll
        for (int r = 0; r < 16; ++r) p0[r] = fexp2(s0[r]);
        #pragma unroll
        for (int r = 0; r < 16; ++r) p1[r] = fexp2(s1[r]);
        float l0 = (((p0[0]+p0[1])+(p0[2]+p0[3])) + ((p0[4]+p0[5])+(p0[6]+p0[7])))
                 + (((p0[8]+p0[9])+(p0[10]+p0[11])) + ((p0[12]+p0[13])+(p0[14]+p0[15])));
        float l1 = (((p1[0]+p1[1])+(p1[2]+p1[3])) + ((p1[4]+p1[5])+(p1[6]+p1[7])))
                 + (((p1[8]+p1[9])+(p1[10]+p1[11])) + ((p1[12]+p1[13])+(p1[14]+p1[15])));
        #pragma unroll
        for (int m = 0; m < 2; ++m) {
            uint4 pbu = uint4{pkbf(p0[8*m+0], p0[8*m+1]), pkbf(p0[8*m+2], p0[8*m+3]),
                              pkbf(p0[8*m+4], p0[8*m+5]), pkbf(p0[8*m+6], p0[8*m+7])};
            short8 pb; __builtin_memcpy(&pb, &pbu, 16);
            const short8 vf = *(const short8*)&Vs[grp][buf][q32][m * 16 + hi * 8];
            ox = __builtin_amdgcn_mfma_f32_32x32x16_bf16(vf, pb, ox, 0, 0, 0);
        }
        #pragma unroll
        for (int m = 0; m < 2; ++m) {
            uint4 pbu = uint4{pkbf(p1[8*m+0], p1[8*m+1]), pkbf(p1[8*m+2], p1[8*m+3]),
                              pkbf(p1[8*m+4], p1[8*m+5]), pkbf(p1[8*m+6], p1[8*m+7])};
            short8 pb; __builtin_memcpy(&pb, &pbu, 16);
            const short8 vf = *(const short8*)&Vs[grp][buf][q32][32 + m * 16 + hi * 8];
            oy = __builtin_amdgcn_mfma_f32_32x32x16_bf16(vf, pb, oy, 0, 0, 0);
        }
        L += l0 + l1;
    };

    // stage each group's tile 0 (2 uint4 K + 2 permuted V rows per thread)
    *(uint4*)&Ks[grp][0][kr][kc * 8]      = *(const uint4*)(kg);
    *(uint4*)&Ks[grp][0][kr + 32][kc * 8] = *(const uint4*)(kg + 1024);
    {
        uint2 a0 = *(const uint2*)(vg),              b0 = *(const uint2*)(vg + 8);
        uint2 a1 = *(const uint2*)(vg + 16 * BNP),   b1 = *(const uint2*)(vg + 16 * BNP + 8);
        *(uint4*)&Vs[grp][0][vr][vc * 8]      = uint4{a0.x, a0.y, b0.x, b0.y};
        *(uint4*)&Vs[grp][0][vr + 16][vc * 8] = uint4{a1.x, a1.y, b1.x, b1.y};
    }
    __syncthreads();

    for (int it = 0; it < 33; ++it) {       // 33 uniform barriers; group 0 idles at it=32
        const int buf = it & 1;
        uint4 kreg0, kreg1; uint2 va0, vb0, va1, vb1;
        const bool pre = (it + 1) < ntiles;
        if (pre) {
            const short* kp = kg + (size_t)(it + 1) * 2048;
            kreg0 = *(const uint4*)(kp);
            kreg1 = *(const uint4*)(kp + 1024);
            const short* vp = vg + (it + 1) * 64;
            va0 = *(const uint2*)(vp);            vb0 = *(const uint2*)(vp + 8);
            va1 = *(const uint2*)(vp + 16 * BNP); vb1 = *(const uint2*)(vp + 16 * BNP + 8);
        }
        if (it < ntiles) {
            __builtin_amdgcn_s_setprio(1);
            if (grp == 0 || it < 32) tile(buf, oAx, oAy, LA);
            else                     tile(buf, oBx, oBx, LB);   // tile 64 = mem segment
            __builtin_amdgcn_s_setprio(0);
        }
        if (pre) {
            *(uint4*)&Ks[grp][buf ^ 1][kr][kc * 8]      = kreg0;
            *(uint4*)&Ks[grp][buf ^ 1][kr + 32][kc * 8] = kreg1;
            *(uint4*)&Vs[grp][buf ^ 1][vr][vc * 8]      = uint4{va0.x, va0.y, vb0.x, vb0.y};
            *(uint4*)&Vs[grp][buf ^ 1][vr + 16][vc * 8] = uint4{va1.x, va1.y, vb1.x, vb1.y};
        }
        __syncthreads();
    }

    // combine the two per-half accumulators
    f32x16 oA = oAx + oAy;
    f32x16 oB = oBx;

    // per-query L: halves split across lane pairs (l, l+32)
    LA += __shfl_xor(LA, 32);
    LB += __shfl_xor(LB, 32);

    // exchange group-0 partials through LDS (reuse Ks; all tile reads are done)
    float* ex = (float*)&Ks[0][0][0][0];    // [w2*64+lane]*20 : oA[16], LA  (10240 B used)
    const int slot = (w2 * 64 + lane) * 20;
    if (grp == 0) {
        #pragma unroll
        for (int i = 0; i < 4; ++i)
            *(f32x4*)(ex + slot + 4 * i) = f32x4{oA[4*i], oA[4*i+1], oA[4*i+2], oA[4*i+3]};
        ex[slot + 16] = LA;
    }
    __syncthreads();

    if (grp == 1 && q < BN) {
        float LT = LA + ex[slot + 16] - 48.f;     // 48 zero-pad keys contributed p=1 each
        const float iA = 1.f / LT, iB = 1.f / LB;
        const int b = bh >> 3, h = bh & 7;
        unsigned short* ap = AO + ((size_t)b * BN + q) * 256 + h * 32;
        #pragma unroll
        for (int k = 0; k < 4; ++k) {
            f32x4 a = *(const f32x4*)(ex + slot + 4 * k);
            float w0 = (oA[4*k+0] + a[0]) * iA + oB[4*k+0] * iB;
            float w1 = (oA[4*k+1] + a[1]) * iA + oB[4*k+1] * iB;
            float w2 = (oA[4*k+2] + a[2]) * iA + oB[4*k+2] * iB;
            float w3 = (oA[4*k+3] + a[3]) * iA + oB[4*k+3] * iB;
            // regs 4k..4k+3 -> hd = 8k + 4*hi + {0..3}
            *(uint2*)(ap + 8 * k + 4 * hi) = uint2{pkbf(w0, w1), pkbf(w2, w3)};
        }
    }
}

// ---------------- output GEMM: bf16 W + XCD-contiguous work decode ----------------
__global__ __launch_bounds__(256)
void gemm_out(const unsigned short* __restrict__ A, const short* __restrict__ Wb,
              const float* __restrict__ bias, float* __restrict__ out)
{
    __shared__ __align__(16) short Ws[2][64][72];
    __shared__ __align__(16) short Ds[2][64][72];

    const int r_ = blockIdx.x & 7;
    const int j_ = blockIdx.x >> 3;           // 0..64
    const int W_ = r_ * 65 + j_;
    if (W_ >= 516) return;                    // uniform early-out, before any barrier
    const int m0i = W_ >> 2, f0i = W_ & 3;

    const int t    = threadIdx.x;
    const int wave = t >> 6, lane = t & 63, q16 = lane & 15, quad = lane >> 4;
    const int f0 = f0i * 64, m0 = m0i * 64;
    const int sr = t >> 2, sc = (t & 3) * 16;
    const int arow = m0 + sr;
    const bool aval = arow < MROWS;
    const short* wp = Wb + (size_t)3 * 65536 + (size_t)(f0 + sr) * 256 + sc;
    const unsigned short* ap = A + (size_t)(aval ? arow : 0) * 256 + sc;

    f32x4 acc[4] = {{0,0,0,0},{0,0,0,0},{0,0,0,0},{0,0,0,0}};

    uint4 wr0, wr1, dr0, dr1;
    {
        wr0 = *(const uint4*)(wp); wr1 = *(const uint4*)(wp + 8);
        dr0 = *(const uint4*)(ap); dr1 = *(const uint4*)(ap + 8);
    }
    *(uint4*)&Ws[0][sr][sc] = wr0; *(uint4*)&Ws[0][sr][sc + 8] = wr1;
    *(uint4*)&Ds[0][sr][sc] = dr0; *(uint4*)&Ds[0][sr][sc + 8] = dr1;
    __syncthreads();

    #pragma unroll
    for (int ki = 0; ki < 4; ++ki) {
        const int buf = ki & 1;
        if (ki < 3) {
            const int k1 = (ki + 1) * 64;
            wr0 = *(const uint4*)(wp + k1); wr1 = *(const uint4*)(wp + k1 + 8);
            dr0 = *(const uint4*)(ap + k1); dr1 = *(const uint4*)(ap + k1 + 8);
        }
        #pragma unroll
        for (int ks = 0; ks < 2; ++ks) {
            const short8 af = *(const short8*)&Ws[buf][wave * 16 + q16][ks * 32 + quad * 8];
            #pragma unroll
            for (int ct = 0; ct < 4; ++ct) {
                const short8 bf = *(const short8*)&Ds[buf][ct * 16 + q16][ks * 32 + quad * 8];
                acc[ct] = __builtin_amdgcn_mfma_f32_16x16x32_bf16(af, bf, acc[ct], 0, 0, 0);
            }
        }
        if (ki < 3) {
            *(uint4*)&Ws[buf ^ 1][sr][sc] = wr0; *(uint4*)&Ws[buf ^ 1][sr][sc + 8] = wr1;
            *(uint4*)&Ds[buf ^ 1][sr][sc] = dr0; *(uint4*)&Ds[buf ^ 1][sr][sc + 8] = dr1;
            __syncthreads();
        }
    }

    const int fbase = f0 + wave * 16 + quad * 4;
    const float4 bb = *(const float4*)(bias + fbase);
    #pragma unroll
    for (int ct = 0; ct < 4; ++ct) {
        int n = m0 + ct * 16 + q16;
        if (n >= MROWS) continue;
        float* op = out + (size_t)n * 256 + fbase;
        *(float4*)op = float4{acc[ct][0] + bb.x, acc[ct][1] + bb.y,
                              acc[ct][2] + bb.z, acc[ct][3] + bb.w};
    }
}

extern "C" void kernel_launch(void* const* d_in, const int* in_sizes, int n_in,
                              void* d_out, int out_size, void* d_ws, size_t ws_size,
                              hipStream_t stream)
{
    (void)in_sizes; (void)n_in; (void)out_size; (void)ws_size;
    const float* q    = (const float*)d_in[0];
    const float* k    = (const float*)d_in[1];
    const float* v    = (const float*)d_in[2];
    const float* fimg = (const float*)d_in[3];
    const float* ftxt = (const float*)d_in[4];
    const float* Wq   = (const float*)d_in[5];
    const float* bq   = (const float*)d_in[6];
    const float* Wk   = (const float*)d_in[7];
    const float* bk   = (const float*)d_in[8];
    const float* Wv   = (const float*)d_in[9];
    const float* bv   = (const float*)d_in[10];
    const float* Wo   = (const float*)d_in[11];
    const float* bo   = (const float*)d_in[12];
    // d_in[13] = num_k_exclude_rope = 64 (compiled in)

    // workspace: Qr bf16 [16][BN][32]; Kr bf16 [16][NKR][32]; Vt bf16 [16][32][BNP];
    // AO bf16 [BB][BN][256]; Wb bf16 [4][256][256]. Total 17,465,344 B (~16.7 MB)
    char* w = (char*)d_ws;
    short*          Qr = (short*)(w);                    //  4,210,688
    short*          Kr = (short*)(w + 4210688);          //  4,259,840
    short*          Vt = (short*)(w + 8470528);          //  4,259,840
    unsigned short* AO = (unsigned short*)(w + 12730368);//  4,210,688
    short*          Wb = (short*)(w + 16941056);         //    524,288

    prep_w<<<dim3(128), 256, 0, stream>>>(Wq, Wk, Wv, Wo, Wb);
    qkv_mfma<<<dim3(1552), 256, 0, stream>>>(q, k, v, Wb, bq, bk, bv,
                                             Qr, Kr, Vt, fimg, ftxt);
    attn_mfma<<<dim3(1040), 256, 0, stream>>>(Qr, Kr, Vt, AO);
    gemm_out<<<dim3(520), 256, 0, stream>>>(AO, Wb, bo, (float*)d_out);
}